// Round 11
// baseline (139.923 us; speedup 1.0000x reference)
//
#include <hip/hip_runtime.h>

// N=524288, D=9, E=2, H=128, M=32, O=2, K=1.
// LAYOUT (confirmed R6): d_in fp32, d_out FP32 (N*2 outputs + 1 loss).
// NUMERICS: pure fp32; per-token fmaf chains identical to accepted kernel.
//
// R11 = R10's K=4 loop + STAGED x (the R9/R10 "unstaged x" was a blind
// spot: FETCH_SIZE only counts HBM — divergent scalar global loads cost
// ~64 serialized L1 line-transactions per wave-instr, ~20-25us/CU, which
// is why R10 (58us) lost to R5 (38.5us) despite half the weight-DS load).
// Measured matrix:  staged x | unstaged x
//   K=2, 4 w/SIMD:   38.5 (R5) |   -
//   K=4, 2 w/SIMD:   THIS      | 58 (R10)
//   K=8, 1 w/SIMD:   52 (R8)   | 53 (R9)
// Weight delivery: 3 broadcast ds_read_b128/j (1-deep rotate); DS floor
// at 2 blocks/CU = 8 waves x 128j x 36cyc = 15.4us; VALU floor 10.2us;
// x: coalesced float4 staging + one-time scattered LDS reads (~1.5us).
// LDS 59.4KB -> 2 blocks/CU (118.9 <= 160KB), launch_bounds(256,2).
#define NTOK 524288
#define TPB  256
#define TOKB 1024             // tokens per block (4 per thread)
#define NBLK (NTOK / TOKB)    // 512 -> 2 blocks/CU

__device__ __forceinline__ float bf2f(unsigned short u) {
    union { unsigned int i; float f; } v;
    v.i = ((unsigned int)u) << 16;
    return v.f;
}

// input load: raw fp32 (bf16-buffer fallback kept purely as safety)
__device__ __forceinline__ float ldq(const void* p, int i, bool f32) {
    if (f32) return ((const float*)p)[i];
    return bf2f(((const unsigned short*)p)[i]);
}

// ---------------------------------------------------------------------------
// Prep: detect buffer dtype (parallel probe), zero counter, stage w_gate,
// fold W2@Wout (+ b2@Wout + bout), pack per-hidden-unit weights.
// wpack layout (expert-major): wpack[e*1536 + j*12 + {0..8:W1col, 9:b1,
// 10..11:W2'}] — 48B records, 16B-aligned.
// ---------------------------------------------------------------------------
__global__ void prep_kernel(const void* __restrict__ num_prop,
                            const void* __restrict__ wgate,
                            const void* __restrict__ W1,
                            const void* __restrict__ b1,
                            const void* __restrict__ W2,
                            const void* __restrict__ b2,
                            const void* __restrict__ Wout,
                            const void* __restrict__ bout,
                            unsigned int* __restrict__ cnt1,
                            int* __restrict__ flag,
                            float* __restrict__ bpp,
                            float* __restrict__ wgf,
                            float* __restrict__ wpack)
{
    __shared__ unsigned int bad;
    __shared__ int sflag;
    const int t = threadIdx.x;
    if (t == 0) { bad = 0u; *cnt1 = 0u; }
    __syncthreads();
    if (t < 72) {   // parallel dtype probe
        const unsigned short* u = (const unsigned short*)num_prop;
        int e = (u[t] >> 7) & 0xFF;
        if (e < 64 || e > 191) atomicOr(&bad, 1u);
    }
    __syncthreads();
    if (t == 0) { sflag = (int)bad; *flag = (int)bad; }
    __syncthreads();
    const bool f32 = (sflag != 0);

    if (t < 18) wgf[t] = ldq(wgate, t, f32);        // w_gate [9,2] raw fp32

    if (t < 4) {  // b''[e][o] = sum_m b2[e][m]*Wout[m][o] + bout[o]
        int e = t >> 1, o = t & 1;
        float acc = ldq(bout, o, f32);
        for (int m = 0; m < 32; ++m)
            acc += ldq(b2, e * 32 + m, f32) * ldq(Wout, m * 2 + o, f32);
        bpp[t] = acc;
    }

    const int e = t >> 7;       // 256 threads -> (e, j)
    const int j = t & 127;
    float p0 = 0.f, p1 = 0.f;
    for (int m = 0; m < 32; ++m) {
        float w = ldq(W2, (e * 128 + j) * 32 + m, f32);
        p0 += w * ldq(Wout, m * 2 + 0, f32);
        p1 += w * ldq(Wout, m * 2 + 1, f32);
    }
    float* dst = wpack + e * 1536 + j * 12;
    #pragma unroll
    for (int d = 0; d < 9; ++d)
        dst[d] = ldq(W1, (e * 9 + d) * 128 + j, f32);
    dst[9]  = ldq(b1, e * 128 + j, f32);
    dst[10] = p0;
    dst[11] = p1;
}

// ---------------------------------------------------------------------------
// Main: 1024 tokens/block, 4/thread, grid 512 (2 blocks/CU, 2 waves/SIMD).
// Stage x (36KB, coalesced float4) + weights (12KB) in LDS. Gate 4 tokens
// (LDS reads), stable partition by expert (16 ballot-chunks = token
// order). Thread handles slots 4*tid..4*tid+3, one expert (<=1 straddler
// per block fixed up after). Main loop: per j, 3 broadcast ds_read_b128
// (1-deep rotate) + 4 independent 9-FMA chains. Results bounce through
// separate 8KB LDS ob -> coalesced float2 stores.
// ---------------------------------------------------------------------------
__global__ __launch_bounds__(TPB, 2)
void moe_main(const void* __restrict__ xg,
              const int* __restrict__ flag,
              const float* __restrict__ wgf,
              const float* __restrict__ bpp,
              const float* __restrict__ wpack,
              unsigned int* __restrict__ cnt1,
              float2* __restrict__ out)
{
    __shared__ __align__(16) float xs[TOKB * 9];   // 36864 B
    __shared__ __align__(16) float wsm[3072];      // 12288 B (both experts)
    __shared__ unsigned short smap[TOKB];          // 2048 B
    __shared__ float2 ob[TOKB];                    // 8192 B
    __shared__ unsigned int wcnt[16];

    const int tid  = threadIdx.x;
    const int lane = tid & 63;
    const int wave = tid >> 6;

    const bool f32 = (*flag) != 0;
    const int tbase = blockIdx.x * TOKB;

    // stage weights: 12 coalesced floats per thread
    #pragma unroll
    for (int i = 0; i < 12; ++i)
        wsm[tid + i * TPB] = wpack[tid + i * TPB];

    if (f32) {   // stage x as float4 (9 per thread, coalesced 16B/lane)
        const float4* xf4 = (const float4*)xg;
        float4* xsv = (float4*)xs;
        const int g4 = blockIdx.x * (TOKB * 9 / 4);
        #pragma unroll
        for (int i = 0; i < 9; ++i)
            xsv[tid + i * TPB] = xf4[g4 + tid + i * TPB];
    } else {
        const unsigned short* xu = (const unsigned short*)xg;
        const int gbase = blockIdx.x * (TOKB * 9);
        for (int i = tid; i < TOKB * 9; i += TPB)
            xs[i] = bf2f(xu[gbase + i]);
    }
    __syncthreads();

    // --- gate 4 tokens (tokens g*256 + tid); chains match accepted kernel ---
    bool e1g[4];
    unsigned long long balg[4];
    #pragma unroll
    for (int g = 0; g < 4; ++g) {
        float l0 = 0.f, l1 = 0.f;
        #pragma unroll
        for (int d = 0; d < 9; ++d) {
            const float xv = xs[(g * 256 + tid) * 9 + d];
            l0 = fmaf(xv, wgf[d * 2 + 0], l0);
            l1 = fmaf(xv, wgf[d * 2 + 1], l1);
        }
        e1g[g] = l1 > l0;          // tie -> expert 0 (stable top_k)
        balg[g] = __ballot(e1g[g]);
        if (lane == 0) wcnt[g * 4 + wave] = (unsigned int)__popcll(balg[g]);
    }
    __syncthreads();

    // --- stable partition over 1024 tokens (chunk c = tok>>6 = token order) ---
    int pres[16]; int run = 0;
    #pragma unroll
    for (int c = 0; c < 16; ++c) { pres[c] = run; run += (int)wcnt[c]; }
    const int n1 = run;
    const int n0 = TOKB - n1;
    const unsigned long long below = (1ull << lane) - 1ull;
    #pragma unroll
    for (int g = 0; g < 4; ++g) {
        const int tok = g * 256 + tid;
        const int pr  = pres[g * 4 + wave] + (int)__popcll(balg[g] & below);
        const int slot = e1g[g] ? (n0 + pr) : (tok - pr);
        smap[slot] = (unsigned short)tok;
    }
    if (tid == 0) atomicAdd(cnt1, (unsigned int)n1);
    __syncthreads();

    // --- this thread processes slots 4*tid .. 4*tid+3 (one expert) ---
    const int s0 = tid * 4;
    int tkv[4];
    #pragma unroll
    for (int k = 0; k < 4; ++k) tkv[k] = (int)smap[s0 + k];
    // permuted x fetch from LDS (one-time scattered b32 reads)
    float x[4][9];
    #pragma unroll
    for (int k = 0; k < 4; ++k) {
        #pragma unroll
        for (int d = 0; d < 9; ++d) x[k][d] = xs[tkv[k] * 9 + d];
    }

    // thread expert: straddler (s0 < n0 < s0+4) -> e0; its e1 slots fixed later
    const int ex = (s0 >= n0) ? 1 : 0;
    const float* wp = wsm + ex * 1536;
    float a0[4], a1[4];
    #pragma unroll
    for (int k = 0; k < 4; ++k) { a0[k] = bpp[ex * 2 + 0]; a1[k] = bpp[ex * 2 + 1]; }

    // main loop: 1-deep rotated DS prefetch; per j: 3 ds_read_b128 + 48 FMA
    const float4* q0 = (const float4*)wp;
    float4 A = q0[0], B = q0[1], C = q0[2];
    for (int j = 0; j < 128; ++j) {
        const int jn = (j + 1) & 127;                 // wraps to 0, harmless
        const float4* qn = (const float4*)(wp + jn * 12);
        const float4 An = qn[0], Bn = qn[1], Cn = qn[2];
        #pragma unroll
        for (int k = 0; k < 4; ++k) {
            float h = C.y;
            h = fmaf(x[k][0], A.x, h); h = fmaf(x[k][1], A.y, h);
            h = fmaf(x[k][2], A.z, h); h = fmaf(x[k][3], A.w, h);
            h = fmaf(x[k][4], B.x, h); h = fmaf(x[k][5], B.y, h);
            h = fmaf(x[k][6], B.z, h); h = fmaf(x[k][7], B.w, h);
            h = fmaf(x[k][8], C.x, h);
            h = fmaxf(h, 0.f);
            a0[k] = fmaf(h, C.z, a0[k]);
            a1[k] = fmaf(h, C.w, a1[k]);
        }
        A = An; B = Bn; C = Cn;
    }

    // --- fixup: straddler's slots n0..n0+nw-1 were computed with e0; lanes
    //     0..nw-1 recompute them with e1 (same per-token chain, bit-exact) ---
    const int nw = (4 - (n0 & 3)) & 3;
    float fx0 = 0.f, fx1 = 0.f; int ftk = 0;
    if (tid < nw) {
        ftk = (int)smap[n0 + tid];
        float xr[9];
        #pragma unroll
        for (int d = 0; d < 9; ++d) xr[d] = xs[ftk * 9 + d];
        fx0 = bpp[2]; fx1 = bpp[3];
        const float* wq = wsm + 1536;
        for (int j = 0; j < 128; ++j) {
            const float4* q = (const float4*)(wq + j * 12);
            const float4 Af = q[0], Bf = q[1], Cf = q[2];
            float h = Cf.y;
            h = fmaf(xr[0], Af.x, h); h = fmaf(xr[1], Af.y, h);
            h = fmaf(xr[2], Af.z, h); h = fmaf(xr[3], Af.w, h);
            h = fmaf(xr[4], Bf.x, h); h = fmaf(xr[5], Bf.y, h);
            h = fmaf(xr[6], Bf.z, h); h = fmaf(xr[7], Bf.w, h);
            h = fmaf(xr[8], Cf.x, h);
            h = fmaxf(h, 0.f);
            fx0 = fmaf(h, Cf.z, fx0);
            fx1 = fmaf(h, Cf.w, fx1);
        }
    }

    // --- bounce through LDS to token order -> coalesced float2 stores ---
    #pragma unroll
    for (int k = 0; k < 4; ++k)
        ob[tkv[k]] = make_float2(a0[k], a1[k]);
    __syncthreads();
    if (tid < nw) ob[ftk] = make_float2(fx0, fx1);   // overwrite wrong-expert
    __syncthreads();
    #pragma unroll
    for (int g = 0; g < 4; ++g)
        out[tbase + g * 256 + tid] = ob[g * 256 + tid];
}

// Loss: gates one-hot value-1.0 -> importance == load == counts.
// cv^2 ddof=1: var=(c0-c1)^2/2, mean=N/2; loss = 0.01*2*cv^2 (~1e-9).
__global__ void finalize_kernel(const unsigned int* __restrict__ cnt1,
                                float* __restrict__ loss_out)
{
    double c1 = (double)(*cnt1);
    double c0 = (double)NTOK - c1;
    double diff = c0 - c1;
    double mean = (double)NTOK * 0.5;
    double var  = 0.5 * diff * diff;
    double cv2  = var / (mean * mean + 1e-10);
    *loss_out = (float)(0.02 * cv2);
}

extern "C" void kernel_launch(void* const* d_in, const int* in_sizes, int n_in,
                              void* d_out, int out_size, void* d_ws, size_t ws_size,
                              hipStream_t stream) {
    const void* num_prop = d_in[0]; // [N,9] fp32
    // d_in[1] = cat_prop (unused)
    const void* w_gate   = d_in[2]; // [9,2]
    const void* W1       = d_in[3]; // [2,9,128]
    const void* b1       = d_in[4]; // [2,128]
    const void* W2       = d_in[5]; // [2,128,32]
    const void* b2       = d_in[6]; // [2,32]
    const void* Wout     = d_in[7]; // [32,2]
    const void* bout     = d_in[8]; // [2]
    // d_in[9] = k (==1)

    char* ws = (char*)d_ws;
    unsigned int* cnt1 = (unsigned int*)ws;          // @0
    int* flag          = (int*)(ws + 8);             // @8
    float* bpp         = (float*)(ws + 16);          // 4 f
    float* wgf         = (float*)(ws + 64);          // 18 f
    float* wpack       = (float*)(ws + 192);         // 3072 f (expert-major)

    float*  outf = (float*)d_out;                    // FP32: N*2 + loss
    float2* out2 = (float2*)d_out;

    hipLaunchKernelGGL(prep_kernel, dim3(1), dim3(256), 0, stream,
                       num_prop, w_gate, W1, b1, W2, b2, Wout, bout,
                       cnt1, flag, bpp, wgf, wpack);
    hipLaunchKernelGGL(moe_main, dim3(NBLK), dim3(TPB), 0, stream,
                       num_prop, flag, wgf, bpp, wpack, cnt1, out2);
    hipLaunchKernelGGL(finalize_kernel, dim3(1), dim3(1), 0, stream,
                       cnt1, outf + (size_t)NTOK * 2);
}